// Round 14
// baseline (183.473 us; speedup 1.0000x reference)
//
#include <hip/hip_runtime.h>
#include <stdint.h>
#include <stddef.h>

// BlockLinear: out[b, g*512+n] = sum_m x[b, g*512+m] * blocks[g, m, n]
// G=8, M=N=512, TOKENS=8192. fp32 in/out; compute in bf16 MFMA.
// Round 14: residency. R13's total regs = 64 VGPR + 64 AGPR(acc) = 128
// -> 16-wave/CU cap (measured 36% occ). Halve the accumulator: wave tile
// 32x64 (acc[2][4] = 32 regs), BM=32 BN=256, grid 4096. launch_bounds
// (256,5) guarantees >=20 waves/CU without R12-style spill (cap ~102).

typedef __attribute__((ext_vector_type(8))) short sv8;   // 8 x bf16 fragment
typedef __attribute__((ext_vector_type(4))) float fv4;   // 4 x f32 accum

__device__ __forceinline__ uint32_t f2bf(float f) {
    union { float f; uint32_t u; } v; v.f = f;
    uint32_t u = v.u;
    u += 0x7FFFu + ((u >> 16) & 1u);   // RNE
    return u >> 16;
}
__device__ __forceinline__ uint32_t pk2(float a, float b) {
    return f2bf(a) | (f2bf(b) << 16);
}

#define BAR()   __builtin_amdgcn_s_barrier()
#define SB0()   __builtin_amdgcn_sched_barrier(0)
#define LGKM0() do { asm volatile("s_waitcnt lgkmcnt(0)" ::: "memory"); SB0(); } while (0)

// bTgl[g][kt] : 2048 units of 16B; unit u = n*4 + c holds
// bf16(blocks[g][kt*32 + c*8 + e][n]), e=0..7.  (fragment-ready layout)
__global__ void bl_pack(const float* __restrict__ blocks,
                        unsigned short* __restrict__ bTgl) {
    __shared__ float tile[64][65];
    const int g  = blockIdx.z;
    const int mt = blockIdx.y;           // 64 m-rows -> kt = mt*2 + {0,1}
    const int n0 = blockIdx.x * 64;
    const float* src = blocks + (size_t)g * 512 * 512;
    const int lane = threadIdx.x & 63;
    const int r0   = threadIdx.x >> 6;   // 0..3
    for (int r = r0; r < 64; r += 4)
        tile[r][lane] = src[(size_t)(mt * 64 + r) * 512 + n0 + lane];
    __syncthreads();
    const int t    = threadIdx.x;        // 0..255
    const int nl   = t >> 2;
    const int c    = t & 3;              // k-chunk == slot (no swizzle)
#pragma unroll
    for (int ktl = 0; ktl < 2; ++ktl) {
        const int mb = ktl * 32 + c * 8;
        uint4 w;
        w.x = pk2(tile[mb + 0][nl], tile[mb + 1][nl]);
        w.y = pk2(tile[mb + 2][nl], tile[mb + 3][nl]);
        w.z = pk2(tile[mb + 4][nl], tile[mb + 5][nl]);
        w.w = pk2(tile[mb + 6][nl], tile[mb + 7][nl]);
        const size_t u = ((size_t)(g * 16 + mt * 2 + ktl)) * 2048 + (n0 + nl) * 4 + c;
        *(uint4*)(bTgl + u * 8) = w;
    }
}

// Main GEMM: BM=32, BN=256, BK=32, 256 threads (4 waves, 1Mx4N),
// wave tile 32x64 = 2x4 fragments of 16x16x32 bf16 MFMA (acc = 32 regs).
// A: LDS dbuf (4 KiB, unioned with epi; 128 threads stage b128).
// B: register prefetch direct from packed global. Epilogue: LDS bounce.
__global__ __launch_bounds__(256, 5) void bl_gemm(
    const float* __restrict__ x,              // [8192][4096]
    const unsigned short* __restrict__ bTgl,  // packed B, see bl_pack
    float* __restrict__ out)                  // [8192][4096]
{
    // union: K-loop uses first 4 KiB as As[2][32*32] bf16;
    // epilogue reuses buffer as epi[16][260] f32 (16640 B).
    __shared__ __align__(16) char ldsbuf[16 * 260 * 4];
    unsigned short* AsP = (unsigned short*)ldsbuf;
    float*          epiP = (float*)ldsbuf;

    const int bid = blockIdx.x;
    const int g   = bid & 7;          // group ~ XCD (round-robin dispatch)
    const int rem = bid >> 3;
    const int nt  = rem & 1;
    const int mt  = rem >> 1;         // 0..255

    const int tid  = threadIdx.x;
    const int lane = tid & 63;
    const int w    = tid >> 6;        // 0..3 = wn
    const int lr   = lane & 15;
    const int lg   = lane >> 4;

    fv4 acc[2][4];
#pragma unroll
    for (int i = 0; i < 2; ++i)
#pragma unroll
        for (int j = 0; j < 4; ++j)
            acc[i][j] = (fv4){0.f, 0.f, 0.f, 0.f};

    const float* xg = x + (size_t)(mt * 32) * 4096 + g * 512;

    // ---- A staging: threads 0..127 -> row arow (0..31), 8-float chunk ----
    const int arow = (tid >> 2) & 31;
    const int ac   = tid & 3;
    const bool doA = tid < 128;
    const float* aSrc = xg + (size_t)arow * 4096 + ac * 8;
    const int aOff = arow * 64 + ((ac ^ ((arow >> 1) & 3)) * 16);  // bytes

    // ---- B fragments: lane-direct from packed layout ----
    const unsigned short* bLane =
        bTgl + ((size_t)(g * 16) * 2048 +
                (size_t)(nt * 256 + w * 64 + lr) * 4 + lg) * 8;

    // ---- A fragment read slot (bytes) ----
    const int slotOff = (lg ^ ((lr >> 1) & 3)) * 16;

    float4 a0_, a1_;       // in-flight A (8 floats)
    sv8 bP[4], bQ[4];      // B fragments: current / next tile

#define ISSUE_A(kt)                                                        \
    do { if (doA) {                                                        \
        const float* s_ = aSrc + (kt) * 32;                                \
        a0_ = *(const float4*)s_;                                          \
        a1_ = *(const float4*)(s_ + 4);                                    \
    } } while (0)

#define ISSUE_BF(kt, dst)                                                  \
    do { _Pragma("unroll") for (int ni = 0; ni < 4; ++ni)                  \
        dst[ni] = *(const sv8*)(bLane + (size_t)(kt) * 16384 + ni * 512);  \
    } while (0)

#define WRITE_A(bufw)                                                      \
    do { if (doA) {                                                        \
        uint4 w_;                                                          \
        w_.x = pk2(a0_.x, a0_.y); w_.y = pk2(a0_.z, a0_.w);                \
        w_.z = pk2(a1_.x, a1_.y); w_.w = pk2(a1_.z, a1_.w);                \
        *(uint4*)((char*)AsP + (bufw) * 2048 + aOff) = w_;                 \
    } } while (0)

#define COMPUTE(rb, breg)                                                  \
    do {                                                                   \
        sv8 a_[2];                                                         \
        _Pragma("unroll") for (int mi = 0; mi < 2; ++mi)                   \
            a_[mi] = *(const sv8*)((const char*)AsP + (rb) * 2048 +        \
                                   (mi * 16 + lr) * 64 + slotOff);         \
        __builtin_amdgcn_s_setprio(1);                                     \
        _Pragma("unroll") for (int mi = 0; mi < 2; ++mi)                   \
        _Pragma("unroll") for (int ni = 0; ni < 4; ++ni)                   \
            acc[mi][ni] = __builtin_amdgcn_mfma_f32_16x16x32_bf16(         \
                breg[ni], a_[mi], acc[mi][ni], 0, 0, 0);                   \
        __builtin_amdgcn_s_setprio(0);                                     \
    } while (0)

    // ---- prologue: tile 0 -> buf0 + bP ----
    ISSUE_BF(0, bP);
    ISSUE_A(0);
    WRITE_A(0);
    LGKM0();
    BAR();

#pragma unroll 1
    for (int kt = 0; kt < 16; kt += 2) {
        const int ka = kt + 1 < 16 ? kt + 1 : 15;
        const int kb = kt + 2 < 16 ? kt + 2 : 15;
        // phase A: tile kt (buf0, bP); stage kt+1
        ISSUE_BF(ka, bQ);
        ISSUE_A(ka);
        COMPUTE(0, bP);
        WRITE_A(1);
        LGKM0();
        BAR();
        // phase B: tile kt+1 (buf1, bQ); stage kt+2
        ISSUE_BF(kb, bP);
        ISSUE_A(kb);
        COMPUTE(1, bQ);
        WRITE_A(0);
        LGKM0();
        BAR();
    }
    // final BAR orders all As reads before epi overwrites the union.

    // ---- epilogue: LDS bounce -> linear 256B-segment stores ----
    float* og = out + (size_t)(mt * 32) * 4096 + g * 512 + nt * 256;
    const int er = tid >> 4;      // 0..15 row within round
    const int ec = tid & 15;      // 16B unit within 256B chunk
#pragma unroll
    for (int mi = 0; mi < 2; ++mi) {
        // deposit: wave w fills cols [w*64, w*64+64) of row lr
#pragma unroll
        for (int ni = 0; ni < 4; ++ni) {
            float4 v;
            v.x = acc[mi][ni][0]; v.y = acc[mi][ni][1];
            v.z = acc[mi][ni][2]; v.w = acc[mi][ni][3];
            *(float4*)&epiP[lr * 260 + w * 64 + ni * 16 + lg * 4] = v;
        }
        __syncthreads();
        // drain: each row (er) covered by 16 threads (ec), 4 passes.
#pragma unroll
        for (int pass = 0; pass < 4; ++pass) {
            const int col = (ec + pass * 16) * 4;
            float4 v = *(float4*)&epiP[er * 260 + col];
            fv4 vv; vv[0] = v.x; vv[1] = v.y; vv[2] = v.z; vv[3] = v.w;
            __builtin_nontemporal_store(
                vv, (fv4*)(og + (size_t)(mi * 16 + er) * 4096 + col));
        }
        __syncthreads();
    }

#undef ISSUE_A
#undef ISSUE_BF
#undef WRITE_A
#undef COMPUTE
}

// Safety net if ws is too small for the packed bf16 blocks (4 MiB).
__global__ void bl_fallback(const float* __restrict__ x,
                            const float* __restrict__ blocks,
                            float* __restrict__ out) {
    const int o = blockIdx.x * 256 + threadIdx.x;
    const int col = o & 4095;
    const int row = o >> 12;
    const int g = col >> 9;
    const int n = col & 511;
    const float* xr = x + (size_t)row * 4096 + g * 512;
    const float* wp = blocks + (size_t)g * 512 * 512 + n;
    float s = 0.f;
    for (int m = 0; m < 512; ++m) s += xr[m] * wp[(size_t)m * 512];
    out[o] = s;
}

extern "C" void kernel_launch(void* const* d_in, const int* in_sizes, int n_in,
                              void* d_out, int out_size, void* d_ws, size_t ws_size,
                              hipStream_t stream) {
    const float* x      = (const float*)d_in[0];
    const float* blocks = (const float*)d_in[1];
    float* out          = (float*)d_out;

    const size_t need = (size_t)8 * 16 * 2048 * 16;   // 4 MiB packed B
    if (ws_size >= need) {
        unsigned short* bTgl = (unsigned short*)d_ws;
        bl_pack<<<dim3(8, 8, 8), 256, 0, stream>>>(blocks, bTgl);
        bl_gemm<<<4096, 256, 0, stream>>>(x, bTgl, out);
    } else {
        bl_fallback<<<(8192 * 4096) / 256, 256, 0, stream>>>(x, blocks, out);
    }
}

// Round 15
// 89.962 us; speedup vs baseline: 2.0394x; 2.0394x over previous
//
#include <hip/hip_runtime.h>
#include <stdint.h>
#include <stddef.h>

// BlockLinear: out[b, g*512+n] = sum_m x[b, g*512+m] * blocks[g, m, n]
// G=8, M=N=512, TOKENS=8192. fp32 in/out; compute in bf16 MFMA.
// Round 15: R14 (BM=32, acc=32 regs -> natural total ~96 regs -> 5
// waves/SIMD residency) but WITHOUT the (256,5) squeeze that spilled
// (R14: VGPR 48/SGPR 32, scratch writebacks 528 MB). (256,4) = same
// bound R13 compiled cleanly under; hardware picks occupancy.

typedef __attribute__((ext_vector_type(8))) short sv8;   // 8 x bf16 fragment
typedef __attribute__((ext_vector_type(4))) float fv4;   // 4 x f32 accum

__device__ __forceinline__ uint32_t f2bf(float f) {
    union { float f; uint32_t u; } v; v.f = f;
    uint32_t u = v.u;
    u += 0x7FFFu + ((u >> 16) & 1u);   // RNE
    return u >> 16;
}
__device__ __forceinline__ uint32_t pk2(float a, float b) {
    return f2bf(a) | (f2bf(b) << 16);
}

#define BAR()   __builtin_amdgcn_s_barrier()
#define SB0()   __builtin_amdgcn_sched_barrier(0)
#define LGKM0() do { asm volatile("s_waitcnt lgkmcnt(0)" ::: "memory"); SB0(); } while (0)

// bTgl[g][kt] : 2048 units of 16B; unit u = n*4 + c holds
// bf16(blocks[g][kt*32 + c*8 + e][n]), e=0..7.  (fragment-ready layout)
__global__ void bl_pack(const float* __restrict__ blocks,
                        unsigned short* __restrict__ bTgl) {
    __shared__ float tile[64][65];
    const int g  = blockIdx.z;
    const int mt = blockIdx.y;           // 64 m-rows -> kt = mt*2 + {0,1}
    const int n0 = blockIdx.x * 64;
    const float* src = blocks + (size_t)g * 512 * 512;
    const int lane = threadIdx.x & 63;
    const int r0   = threadIdx.x >> 6;   // 0..3
    for (int r = r0; r < 64; r += 4)
        tile[r][lane] = src[(size_t)(mt * 64 + r) * 512 + n0 + lane];
    __syncthreads();
    const int t    = threadIdx.x;        // 0..255
    const int nl   = t >> 2;
    const int c    = t & 3;              // k-chunk == slot (no swizzle)
#pragma unroll
    for (int ktl = 0; ktl < 2; ++ktl) {
        const int mb = ktl * 32 + c * 8;
        uint4 w;
        w.x = pk2(tile[mb + 0][nl], tile[mb + 1][nl]);
        w.y = pk2(tile[mb + 2][nl], tile[mb + 3][nl]);
        w.z = pk2(tile[mb + 4][nl], tile[mb + 5][nl]);
        w.w = pk2(tile[mb + 6][nl], tile[mb + 7][nl]);
        const size_t u = ((size_t)(g * 16 + mt * 2 + ktl)) * 2048 + (n0 + nl) * 4 + c;
        *(uint4*)(bTgl + u * 8) = w;
    }
}

// Main GEMM: BM=32, BN=256, BK=32, 256 threads (4 waves, 1Mx4N),
// wave tile 32x64 = 2x4 fragments of 16x16x32 bf16 MFMA (acc = 32 regs).
// A: LDS dbuf (4 KiB, unioned with epi; threads 0..127 stage).
// B: register prefetch direct from packed global. Epilogue: LDS bounce.
__global__ __launch_bounds__(256, 4) void bl_gemm(
    const float* __restrict__ x,              // [8192][4096]
    const unsigned short* __restrict__ bTgl,  // packed B, see bl_pack
    float* __restrict__ out)                  // [8192][4096]
{
    // union: K-loop uses first 4 KiB as As[2][32*32] bf16;
    // epilogue reuses buffer as epi[16][260] f32 (16640 B).
    __shared__ __align__(16) char ldsbuf[16 * 260 * 4];
    unsigned short* AsP = (unsigned short*)ldsbuf;
    float*          epiP = (float*)ldsbuf;

    const int bid = blockIdx.x;
    const int g   = bid & 7;          // group ~ XCD (round-robin dispatch)
    const int rem = bid >> 3;
    const int nt  = rem & 1;
    const int mt  = rem >> 1;         // 0..255

    const int tid  = threadIdx.x;
    const int lane = tid & 63;
    const int w    = tid >> 6;        // 0..3 = wn
    const int lr   = lane & 15;
    const int lg   = lane >> 4;

    fv4 acc[2][4];
#pragma unroll
    for (int i = 0; i < 2; ++i)
#pragma unroll
        for (int j = 0; j < 4; ++j)
            acc[i][j] = (fv4){0.f, 0.f, 0.f, 0.f};

    const float* xg = x + (size_t)(mt * 32) * 4096 + g * 512;

    // ---- A staging: threads 0..127 -> row arow (0..31), 8-float chunk ----
    const int arow = (tid >> 2) & 31;
    const int ac   = tid & 3;
    const bool doA = tid < 128;
    const float* aSrc = xg + (size_t)arow * 4096 + ac * 8;
    const int aOff = arow * 64 + ((ac ^ ((arow >> 1) & 3)) * 16);  // bytes

    // ---- B fragments: lane-direct from packed layout ----
    const unsigned short* bLane =
        bTgl + ((size_t)(g * 16) * 2048 +
                (size_t)(nt * 256 + w * 64 + lr) * 4 + lg) * 8;

    // ---- A fragment read slot (bytes) ----
    const int slotOff = (lg ^ ((lr >> 1) & 3)) * 16;

    float4 a0_, a1_;       // in-flight A (8 floats)
    sv8 bP[4], bQ[4];      // B fragments: current / next tile

#define ISSUE_A(kt)                                                        \
    do { if (doA) {                                                        \
        const float* s_ = aSrc + (kt) * 32;                                \
        a0_ = *(const float4*)s_;                                          \
        a1_ = *(const float4*)(s_ + 4);                                    \
    } } while (0)

#define ISSUE_BF(kt, dst)                                                  \
    do { _Pragma("unroll") for (int ni = 0; ni < 4; ++ni)                  \
        dst[ni] = *(const sv8*)(bLane + (size_t)(kt) * 16384 + ni * 512);  \
    } while (0)

#define WRITE_A(bufw)                                                      \
    do { if (doA) {                                                        \
        uint4 w_;                                                          \
        w_.x = pk2(a0_.x, a0_.y); w_.y = pk2(a0_.z, a0_.w);                \
        w_.z = pk2(a1_.x, a1_.y); w_.w = pk2(a1_.z, a1_.w);                \
        *(uint4*)((char*)AsP + (bufw) * 2048 + aOff) = w_;                 \
    } } while (0)

#define COMPUTE(rb, breg)                                                  \
    do {                                                                   \
        sv8 a_[2];                                                         \
        _Pragma("unroll") for (int mi = 0; mi < 2; ++mi)                   \
            a_[mi] = *(const sv8*)((const char*)AsP + (rb) * 2048 +        \
                                   (mi * 16 + lr) * 64 + slotOff);         \
        __builtin_amdgcn_s_setprio(1);                                     \
        _Pragma("unroll") for (int mi = 0; mi < 2; ++mi)                   \
        _Pragma("unroll") for (int ni = 0; ni < 4; ++ni)                   \
            acc[mi][ni] = __builtin_amdgcn_mfma_f32_16x16x32_bf16(         \
                breg[ni], a_[mi], acc[mi][ni], 0, 0, 0);                   \
        __builtin_amdgcn_s_setprio(0);                                     \
    } while (0)

    // ---- prologue: tile 0 -> buf0 + bP ----
    ISSUE_BF(0, bP);
    ISSUE_A(0);
    WRITE_A(0);
    LGKM0();
    BAR();

#pragma unroll 1
    for (int kt = 0; kt < 16; kt += 2) {
        const int ka = kt + 1 < 16 ? kt + 1 : 15;
        const int kb = kt + 2 < 16 ? kt + 2 : 15;
        // phase A: tile kt (buf0, bP); stage kt+1
        ISSUE_BF(ka, bQ);
        ISSUE_A(ka);
        COMPUTE(0, bP);
        WRITE_A(1);
        LGKM0();
        BAR();
        // phase B: tile kt+1 (buf1, bQ); stage kt+2
        ISSUE_BF(kb, bP);
        ISSUE_A(kb);
        COMPUTE(1, bQ);
        WRITE_A(0);
        LGKM0();
        BAR();
    }
    // final BAR orders all As reads before epi overwrites the union.

    // ---- epilogue: LDS bounce -> linear 256B-segment stores ----
    float* og = out + (size_t)(mt * 32) * 4096 + g * 512 + nt * 256;
    const int er = tid >> 4;      // 0..15 row within round
    const int ec = tid & 15;      // 16B unit within 256B chunk
#pragma unroll
    for (int mi = 0; mi < 2; ++mi) {
        // deposit: wave w fills cols [w*64, w*64+64) of row lr
#pragma unroll
        for (int ni = 0; ni < 4; ++ni) {
            float4 v;
            v.x = acc[mi][ni][0]; v.y = acc[mi][ni][1];
            v.z = acc[mi][ni][2]; v.w = acc[mi][ni][3];
            *(float4*)&epiP[lr * 260 + w * 64 + ni * 16 + lg * 4] = v;
        }
        __syncthreads();
        // drain: each row (er) covered by 16 threads (ec), 4 passes.
#pragma unroll
        for (int pass = 0; pass < 4; ++pass) {
            const int col = (ec + pass * 16) * 4;
            float4 v = *(float4*)&epiP[er * 260 + col];
            fv4 vv; vv[0] = v.x; vv[1] = v.y; vv[2] = v.z; vv[3] = v.w;
            __builtin_nontemporal_store(
                vv, (fv4*)(og + (size_t)(mi * 16 + er) * 4096 + col));
        }
        __syncthreads();
    }

#undef ISSUE_A
#undef ISSUE_BF
#undef WRITE_A
#undef COMPUTE
}

// Safety net if ws is too small for the packed bf16 blocks (4 MiB).
__global__ void bl_fallback(const float* __restrict__ x,
                            const float* __restrict__ blocks,
                            float* __restrict__ out) {
    const int o = blockIdx.x * 256 + threadIdx.x;
    const int col = o & 4095;
    const int row = o >> 12;
    const int g = col >> 9;
    const int n = col & 511;
    const float* xr = x + (size_t)row * 4096 + g * 512;
    const float* wp = blocks + (size_t)g * 512 * 512 + n;
    float s = 0.f;
    for (int m = 0; m < 512; ++m) s += xr[m] * wp[(size_t)m * 512];
    out[o] = s;
}

extern "C" void kernel_launch(void* const* d_in, const int* in_sizes, int n_in,
                              void* d_out, int out_size, void* d_ws, size_t ws_size,
                              hipStream_t stream) {
    const float* x      = (const float*)d_in[0];
    const float* blocks = (const float*)d_in[1];
    float* out          = (float*)d_out;

    const size_t need = (size_t)8 * 16 * 2048 * 16;   // 4 MiB packed B
    if (ws_size >= need) {
        unsigned short* bTgl = (unsigned short*)d_ws;
        bl_pack<<<dim3(8, 8, 8), 256, 0, stream>>>(blocks, bTgl);
        bl_gemm<<<4096, 256, 0, stream>>>(x, bTgl, out);
    } else {
        bl_fallback<<<(8192 * 4096) / 256, 256, 0, stream>>>(x, blocks, out);
    }
}

// Round 16
// 62.908 us; speedup vs baseline: 2.9165x; 1.4301x over previous
//
#include <hip/hip_runtime.h>
#include <stdint.h>
#include <stddef.h>

// BlockLinear: out[b, g*512+n] = sum_m x[b, g*512+m] * blocks[g, m, n]
// G=8, M=N=512, TOKENS=8192. fp32 in/out; compute in bf16 MFMA.
// Round 16: R13 + 2-deep A register prefetch (the only untested chain):
// phase(t) issues A(t+2) into the free pair and writes A(t+1) issued a
// full phase (~900cyc) earlier -> the per-phase vmcnt stall before
// WRITE_A collapses. +8 VGPR; launch_bounds (256,3) gives headroom
// (no R12/R14-style allocator squeeze; 12-wave cap == R13's measured).

typedef __attribute__((ext_vector_type(8))) short sv8;   // 8 x bf16 fragment
typedef __attribute__((ext_vector_type(4))) float fv4;   // 4 x f32 accum

__device__ __forceinline__ uint32_t f2bf(float f) {
    union { float f; uint32_t u; } v; v.f = f;
    uint32_t u = v.u;
    u += 0x7FFFu + ((u >> 16) & 1u);   // RNE
    return u >> 16;
}
__device__ __forceinline__ uint32_t pk2(float a, float b) {
    return f2bf(a) | (f2bf(b) << 16);
}

#define BAR()   __builtin_amdgcn_s_barrier()
#define SB0()   __builtin_amdgcn_sched_barrier(0)
#define LGKM0() do { asm volatile("s_waitcnt lgkmcnt(0)" ::: "memory"); SB0(); } while (0)

// bTgl[g][kt] : 2048 units of 16B; unit u = n*4 + c holds
// bf16(blocks[g][kt*32 + c*8 + e][n]), e=0..7.  (fragment-ready layout)
__global__ void bl_pack(const float* __restrict__ blocks,
                        unsigned short* __restrict__ bTgl) {
    __shared__ float tile[64][65];
    const int g  = blockIdx.z;
    const int mt = blockIdx.y;           // 64 m-rows -> kt = mt*2 + {0,1}
    const int n0 = blockIdx.x * 64;
    const float* src = blocks + (size_t)g * 512 * 512;
    const int lane = threadIdx.x & 63;
    const int r0   = threadIdx.x >> 6;   // 0..3
    for (int r = r0; r < 64; r += 4)
        tile[r][lane] = src[(size_t)(mt * 64 + r) * 512 + n0 + lane];
    __syncthreads();
    const int t    = threadIdx.x;        // 0..255
    const int nl   = t >> 2;
    const int c    = t & 3;              // k-chunk == slot (no swizzle)
#pragma unroll
    for (int ktl = 0; ktl < 2; ++ktl) {
        const int mb = ktl * 32 + c * 8;
        uint4 w;
        w.x = pk2(tile[mb + 0][nl], tile[mb + 1][nl]);
        w.y = pk2(tile[mb + 2][nl], tile[mb + 3][nl]);
        w.z = pk2(tile[mb + 4][nl], tile[mb + 5][nl]);
        w.w = pk2(tile[mb + 6][nl], tile[mb + 7][nl]);
        const size_t u = ((size_t)(g * 16 + mt * 2 + ktl)) * 2048 + (n0 + nl) * 4 + c;
        *(uint4*)(bTgl + u * 8) = w;
    }
}

// Main GEMM: BM=64, BN=256, BK=32, 256 threads (4 waves, 1Mx4N),
// wave tile 64x64 = 4x4 fragments of 16x16x32 bf16 MFMA.
// A: LDS dbuf (8 KiB, unioned with epi), 2-deep register prefetch.
// B: 1-deep register prefetch direct from packed global (covered).
// Epilogue: LDS bounce -> 256B-linear nontemporal stores.
__global__ __launch_bounds__(256, 3) void bl_gemm(
    const float* __restrict__ x,              // [8192][4096]
    const unsigned short* __restrict__ bTgl,  // packed B, see bl_pack
    float* __restrict__ out)                  // [8192][4096]
{
    // union: K-loop uses first 8 KiB as As[2][64*32] bf16;
    // epilogue reuses buffer as epi[16][260] f32 (16640 B).
    __shared__ __align__(16) char ldsbuf[16 * 260 * 4];
    unsigned short* AsP = (unsigned short*)ldsbuf;
    float*          epiP = (float*)ldsbuf;

    const int bid = blockIdx.x;
    const int g   = bid & 7;          // group ~ XCD (round-robin dispatch)
    const int rem = bid >> 3;
    const int nt  = rem & 1;
    const int mt  = rem >> 1;         // 0..127

    const int tid  = threadIdx.x;
    const int lane = tid & 63;
    const int w    = tid >> 6;        // 0..3 = wn
    const int lr   = lane & 15;
    const int lg   = lane >> 4;

    fv4 acc[4][4];
#pragma unroll
    for (int i = 0; i < 4; ++i)
#pragma unroll
        for (int j = 0; j < 4; ++j)
            acc[i][j] = (fv4){0.f, 0.f, 0.f, 0.f};

    const float* xg = x + (size_t)(mt * 64) * 4096 + g * 512;

    // ---- A staging: thread -> row arow (0..63), 8-float chunk ac (0..3) ----
    const int arow = tid >> 2;
    const int ac   = tid & 3;
    const float* aSrc = xg + (size_t)arow * 4096 + ac * 8;
    const int aOff = arow * 64 + ((ac ^ ((arow >> 1) & 3)) * 16);  // bytes

    // ---- B fragments: lane-direct from packed layout ----
    const unsigned short* bLane =
        bTgl + ((size_t)(g * 16) * 2048 +
                (size_t)(nt * 256 + w * 64 + lr) * 4 + lg) * 8;

    // ---- A fragment read slot (bytes) ----
    const int slotOff = (lg ^ ((lr >> 1) & 3)) * 16;

    float4 arP0_, arP1_, arQ0_, arQ1_;   // 2-deep in-flight A (8 floats each)
    sv8 bP[4], bQ[4];                    // B fragments: current / next tile

#define ISSUE_A(kt, r0_, r1_)                                              \
    do {                                                                   \
        const float* s_ = aSrc + (kt) * 32;                                \
        r0_ = *(const float4*)s_;                                          \
        r1_ = *(const float4*)(s_ + 4);                                    \
    } while (0)

#define ISSUE_BF(kt, dst)                                                  \
    do { _Pragma("unroll") for (int ni = 0; ni < 4; ++ni)                  \
        dst[ni] = *(const sv8*)(bLane + (size_t)(kt) * 16384 + ni * 512);  \
    } while (0)

#define WRITE_A(bufw, r0_, r1_)                                            \
    do {                                                                   \
        uint4 w_;                                                          \
        w_.x = pk2(r0_.x, r0_.y); w_.y = pk2(r0_.z, r0_.w);                \
        w_.z = pk2(r1_.x, r1_.y); w_.w = pk2(r1_.z, r1_.w);                \
        *(uint4*)((char*)AsP + (bufw) * 4096 + aOff) = w_;                 \
    } while (0)

#define COMPUTE(rb, breg)                                                  \
    do {                                                                   \
        sv8 a_[4];                                                         \
        _Pragma("unroll") for (int mi = 0; mi < 4; ++mi)                   \
            a_[mi] = *(const sv8*)((const char*)AsP + (rb) * 4096 +        \
                                   (mi * 16 + lr) * 64 + slotOff);         \
        __builtin_amdgcn_s_setprio(1);                                     \
        _Pragma("unroll") for (int mi = 0; mi < 4; ++mi)                   \
        _Pragma("unroll") for (int ni = 0; ni < 4; ++ni)                   \
            acc[mi][ni] = __builtin_amdgcn_mfma_f32_16x16x32_bf16(         \
                breg[ni], a_[mi], acc[mi][ni], 0, 0, 0);                   \
        __builtin_amdgcn_s_setprio(0);                                     \
    } while (0)

    // ---- prologue: tile 0 -> buf0 + bP; A(1) in flight (pair P) ----
    ISSUE_BF(0, bP);
    ISSUE_A(0, arP0_, arP1_);
    WRITE_A(0, arP0_, arP1_);
    ISSUE_A(1, arP0_, arP1_);
    LGKM0();
    BAR();

#pragma unroll 1
    for (int kt = 0; kt < 16; kt += 2) {
        const int ka = kt + 2 < 16 ? kt + 2 : 15;
        const int kb = kt + 3 < 16 ? kt + 3 : 15;
        // phase A: tile kt (buf0, bP). P holds A(kt+1), issued a phase ago.
        ISSUE_BF(kt + 1, bQ);
        ISSUE_A(ka, arQ0_, arQ1_);          // A(kt+2) -> Q
        COMPUTE(0, bP);
        WRITE_A(1, arP0_, arP1_);           // A(kt+1), loads long since landed
        LGKM0();
        BAR();
        // phase B: tile kt+1 (buf1, bQ). Q holds A(kt+2).
        ISSUE_BF(ka, bP);
        ISSUE_A(kb, arP0_, arP1_);          // A(kt+3) -> P
        COMPUTE(1, bQ);
        WRITE_A(0, arQ0_, arQ1_);           // A(kt+2)
        LGKM0();
        BAR();
    }
    // final BAR orders all As reads before epi overwrites the union.

    // ---- epilogue: LDS bounce -> linear 256B-segment stores ----
    float* og = out + (size_t)(mt * 64) * 4096 + g * 512 + nt * 256;
    const int er = tid >> 4;      // 0..15 row within round
    const int ec = tid & 15;      // 16B unit within 256B chunk
#pragma unroll
    for (int mi = 0; mi < 4; ++mi) {
        // deposit: wave w fills cols [w*64, w*64+64) of row lr
#pragma unroll
        for (int ni = 0; ni < 4; ++ni) {
            float4 v;
            v.x = acc[mi][ni][0]; v.y = acc[mi][ni][1];
            v.z = acc[mi][ni][2]; v.w = acc[mi][ni][3];
            *(float4*)&epiP[lr * 260 + w * 64 + ni * 16 + lg * 4] = v;
        }
        __syncthreads();
        // drain: each row (er) covered by 16 threads (ec), 4 passes.
#pragma unroll
        for (int pass = 0; pass < 4; ++pass) {
            const int col = (ec + pass * 16) * 4;
            float4 v = *(float4*)&epiP[er * 260 + col];
            fv4 vv; vv[0] = v.x; vv[1] = v.y; vv[2] = v.z; vv[3] = v.w;
            __builtin_nontemporal_store(
                vv, (fv4*)(og + (size_t)(mi * 16 + er) * 4096 + col));
        }
        __syncthreads();
    }

#undef ISSUE_A
#undef ISSUE_BF
#undef WRITE_A
#undef COMPUTE
}

// Safety net if ws is too small for the packed bf16 blocks (4 MiB).
__global__ void bl_fallback(const float* __restrict__ x,
                            const float* __restrict__ blocks,
                            float* __restrict__ out) {
    const int o = blockIdx.x * 256 + threadIdx.x;
    const int col = o & 4095;
    const int row = o >> 12;
    const int g = col >> 9;
    const int n = col & 511;
    const float* xr = x + (size_t)row * 4096 + g * 512;
    const float* wp = blocks + (size_t)g * 512 * 512 + n;
    float s = 0.f;
    for (int m = 0; m < 512; ++m) s += xr[m] * wp[(size_t)m * 512];
    out[o] = s;
}

extern "C" void kernel_launch(void* const* d_in, const int* in_sizes, int n_in,
                              void* d_out, int out_size, void* d_ws, size_t ws_size,
                              hipStream_t stream) {
    const float* x      = (const float*)d_in[0];
    const float* blocks = (const float*)d_in[1];
    float* out          = (float*)d_out;

    const size_t need = (size_t)8 * 16 * 2048 * 16;   // 4 MiB packed B
    if (ws_size >= need) {
        unsigned short* bTgl = (unsigned short*)d_ws;
        bl_pack<<<dim3(8, 8, 8), 256, 0, stream>>>(blocks, bTgl);
        bl_gemm<<<2048, 256, 0, stream>>>(x, bTgl, out);
    } else {
        bl_fallback<<<(8192 * 4096) / 256, 256, 0, stream>>>(x, blocks, out);
    }
}